// Round 1
// baseline (772.180 us; speedup 1.0000x reference)
//
#include <hip/hip_runtime.h>
#include <cstdint>
#include <cstddef>

// ---------------------------------------------------------------------------
// Problem constants
// ---------------------------------------------------------------------------
#define NT      16384      // B*T tokens
#define DIM     768
#define TT      32         // tokens per block
#define KC      8          // K-chunk
#define NCH     (DIM/KC)   // 96 chunks
#define NOUTC   512        // concat outputs: [0,256) base-W1 | [256,384) Wa' | [384,512) Wb
#define ALPHA_OFF 802816   // NT*49

// ws layout (floats)
#define WS_WCAT   0          // 768*512 = 393216
#define WS_GA     393216     // 128
#define WS_CBIAS  393344     // 128
#define WS_V1     393472     // 128
#define WS_V2     393600     // 128
#define WS_V3     393728     // 128
#define WS_CHEFF  393856     // 512 (transposed [k][m])
#define WS_C4     394368     // 4

__device__ __forceinline__ float silu_f(float x) { return x / (1.0f + expf(-x)); }

// ---------------------------------------------------------------------------
// Prep A: build concatenated, pre-transposed weight panel wcat[k][j], k<768,j<512
//   j <  256 : base_w1[j][k]
//   j <  384 : mlp_w1[j-256][k] * ln_g[k]     (LN-scale folded in)
//   else     : mlp_w1[j-384][768+k]
// ---------------------------------------------------------------------------
__global__ void k_prep_wcat(const float* __restrict__ bw1, const float* __restrict__ mw1,
                            const float* __restrict__ g, float* __restrict__ wcat) {
    int idx = blockIdx.x * 256 + threadIdx.x;  // 0..393215
    int k = idx >> 9, j = idx & 511;
    float v;
    if (j < 256)       v = bw1[j * DIM + k];
    else if (j < 384)  v = mw1[(size_t)(j - 256) * 1540 + k] * g[k];
    else               v = mw1[(size_t)(j - 384) * 1540 + 768 + k];
    wcat[idx] = v;
}

// ---------------------------------------------------------------------------
// Prep B: small precomputes.
//   gA[j]    = sum_k ln_g[k]*mlp_w1[j][k]
//   cbias[j] = (ln_b @ W1a)[j] + pf*mlp_w1[j][1539] + mlp_b1[j]
//   v1/v2/v3 = mlp_w1[:,1536/1537/1538]
//   cheff_t[k][m] = ch_w[m][k] + sum_kk u[kk]*bil_w[m*32+kk][k]
//   c4[m]    = ch_b[m] + ph_b[m] + mode_bias[m] + u·ph_w[m]
// ---------------------------------------------------------------------------
__global__ void k_prep_small(const float* __restrict__ mw1, const float* __restrict__ mb1,
                             const float* __restrict__ g, const float* __restrict__ lnb,
                             const float* __restrict__ pe, const float* __restrict__ chw,
                             const float* __restrict__ chb, const float* __restrict__ phw,
                             const float* __restrict__ phb, const float* __restrict__ bil,
                             const float* __restrict__ mob, const int* __restrict__ pidxp,
                             float* __restrict__ gA, float* __restrict__ cbias,
                             float* __restrict__ v1, float* __restrict__ v2,
                             float* __restrict__ v3, float* __restrict__ cheff_t,
                             float* __restrict__ c4) {
    __shared__ float u[32];
    int tid = threadIdx.x;
    int pidx = *pidxp;
    if (tid < 32) u[tid] = pe[pidx * 32 + tid];
    __syncthreads();
    {
        int j = tid >> 1, half = tid & 1;
        const float* row = mw1 + (size_t)j * 1540 + half * 384;
        const float* gp = g + half * 384;
        const float* bp = lnb + half * 384;
        float sg_ = 0.f, sb_ = 0.f;
        for (int k = 0; k < 384; k += 4) {
            float4 rv = *(const float4*)(row + k);
            float4 gv = *(const float4*)(gp + k);
            float4 bv = *(const float4*)(bp + k);
            sg_ += rv.x * gv.x + rv.y * gv.y + rv.z * gv.z + rv.w * gv.w;
            sb_ += rv.x * bv.x + rv.y * bv.y + rv.z * bv.z + rv.w * bv.w;
        }
        sg_ += __shfl_xor(sg_, 1);
        sb_ += __shfl_xor(sb_, 1);
        if (half == 0) {
            const float* rowf = mw1 + (size_t)j * 1540;
            float pf = (float)pidx * (1.0f / 11.0f);
            gA[j] = sg_;
            v1[j] = rowf[1536];
            v2[j] = rowf[1537];
            v3[j] = rowf[1538];
            cbias[j] = sb_ + pf * rowf[1539] + mb1[j];
        }
    }
    for (int idx = tid; idx < 512; idx += 256) {
        int k = idx >> 2, m = idx & 3;
        float s = chw[m * 128 + k];
        for (int kk = 0; kk < 32; kk++) s += u[kk] * bil[(size_t)(m * 32 + kk) * 128 + k];
        cheff_t[k * 4 + m] = s;
    }
    if (tid < 4) {
        float s = chb[tid] + phb[tid] + mob[tid];
        for (int kk = 0; kk < 32; kk++) s += u[kk] * phw[tid * 32 + kk];
        c4[tid] = s;
    }
}

// ---------------------------------------------------------------------------
// Main fused kernel. 512 blocks x 256 threads, 32 tokens per block.
// Shared layout (floats), total 15872 floats = 63.5 KB:
//   [0,9216)      : union { staging: wbuf[2][4096] @0, abuf[2][512] @8192 }
//                         { a1[32][256] @0 }  { cbuf[32][132] @0 (after a1 dead) }
//   [9216,13312)  : c1[32][128]
//   [13312,14880) : basebuf[32][49]
//   [14880,15136) : stats[32][8]  (m, istd, mean_ll, std_ll, dmu)
//   [15136,15648) : cheff_s[512]
//   [15648,15776) : alpha_s[32][4]
//   [15776,15780) : c4_s
//   [15780,15808) : msw_s[28]
//   [15808,15857) : sg_s[49] (ints)
// ---------------------------------------------------------------------------
__device__ __forceinline__ void load_w_regs(const float* __restrict__ wcat, int c, int tid,
                                            float4 w[4]) {
    const float* s = wcat + (size_t)c * 4096 + tid * 4;
    w[0] = *(const float4*)(s);
    w[1] = *(const float4*)(s + 1024);
    w[2] = *(const float4*)(s + 2048);
    w[3] = *(const float4*)(s + 3072);
}
__device__ __forceinline__ void store_w_lds(float* wb, int tid, const float4 w[4]) {
    *(float4*)(wb + tid * 4) = w[0];
    *(float4*)(wb + 1024 + tid * 4) = w[1];
    *(float4*)(wb + 2048 + tid * 4) = w[2];
    *(float4*)(wb + 3072 + tid * 4) = w[3];
}
__device__ __forceinline__ float4 load_a_reg(const float* __restrict__ h,
                                             const float* __restrict__ ex, int tok0, int c,
                                             int tid) {
    if (tid < 128) {
        int t = (tid & 63) >> 1, half = tid & 1;
        const float* src = (tid < 64 ? h : ex) + (size_t)(tok0 + t) * DIM + c * KC + half * 4;
        return *(const float4*)src;
    }
    return make_float4(0.f, 0.f, 0.f, 0.f);
}
__device__ __forceinline__ void store_a_lds(float* ab, int tid, float4 a) {
    if (tid < 128) {
        int t = (tid & 63) >> 1, half = tid & 1, asel = (tid < 64) ? 0 : 32;
        float* d = ab + (half * 4) * 64 + asel + t;  // row stride 64: [k][t]
        d[0] = a.x; d[64] = a.y; d[128] = a.z; d[192] = a.w;
    }
}

__launch_bounds__(256, 2)
__global__ void k_main(const float* __restrict__ h, const float* __restrict__ ex,
                       const float* __restrict__ lam, const float* __restrict__ mup,
                       const float* __restrict__ bb1, const float* __restrict__ bw2,
                       const float* __restrict__ bb2, const float* __restrict__ mw2,
                       const float* __restrict__ mb2, const float* __restrict__ msw,
                       const int* __restrict__ sg, const float* __restrict__ wcat,
                       const float* __restrict__ gA, const float* __restrict__ cbias,
                       const float* __restrict__ v1w, const float* __restrict__ v2w,
                       const float* __restrict__ v3w, const float* __restrict__ cheff_t,
                       const float* __restrict__ c4, float* __restrict__ out) {
    __shared__ float F[15872];
    float* c1      = F + 9216;
    float* basebuf = F + 13312;
    float* stats   = F + 14880;
    float* cheff_s = F + 15136;
    float* alpha_s = F + 15648;
    float* c4_s    = F + 15776;
    float* msw_s   = F + 15780;
    int*   sg_s    = (int*)(F + 15808);

    const int tid = threadIdx.x;
    const int bid = blockIdx.x;
    const int tok0 = bid * TT;

    // --- small constant preloads ---
    if (tid < 49) sg_s[tid] = sg[tid];
    if (tid >= 64 && tid < 92) msw_s[tid - 64] = msw[tid - 64];
    if (tid >= 96 && tid < 100) c4_s[tid - 96] = c4[tid - 96];
    for (int i = tid; i < 512; i += 256) cheff_s[i] = cheff_t[i];

    // --- stats pass: 8 threads per token ---
    {
        int t = tid >> 3, r = tid & 7;
        const float* hp = h + (size_t)(tok0 + t) * DIM;
        const float* lp = lam + (size_t)(tok0 + t) * DIM;
        const float* mp = mup + (size_t)(tok0 + t) * DIM;
        float sh = 0.f, sh2 = 0.f, sll = 0.f, sll2 = 0.f, sd = 0.f;
        for (int i = 0; i < 24; i++) {
            int k0 = i * 32 + r * 4;
            float4 hv = *(const float4*)(hp + k0);
            float4 lv = *(const float4*)(lp + k0);
            float4 mv = *(const float4*)(mp + k0);
#pragma unroll
            for (int e = 0; e < 4; e++) {
                float hx = (&hv.x)[e];
                float lx = fmaxf((&lv.x)[e], 1e-6f);
                float mx = (&mv.x)[e];
                sh += hx; sh2 += hx * hx;
                float ll = logf(lx);
                sll += ll; sll2 += ll * ll;
                float dd = hx - mx; sd += dd * dd;
            }
        }
#pragma unroll
        for (int off = 1; off < 8; off <<= 1) {
            sh += __shfl_xor(sh, off);  sh2 += __shfl_xor(sh2, off);
            sll += __shfl_xor(sll, off); sll2 += __shfl_xor(sll2, off);
            sd += __shfl_xor(sd, off);
        }
        if (r == 0) {
            float m = sh * (1.f / 768.f);
            float var = sh2 * (1.f / 768.f) - m * m;
            float istd = rsqrtf(var + 1e-5f);
            float mll = sll * (1.f / 768.f);
            float vll = (sll2 - 768.f * mll * mll) * (1.f / 767.f);
            float sstd = fmaxf(sqrtf(fmaxf(vll, 0.f)), 1e-6f);
            float dmu = sqrtf(sd * (1.f / 768.f) + 1e-8f);
            float* st = stats + t * 8;
            st[0] = m; st[1] = istd; st[2] = mll; st[3] = sstd; st[4] = dmu;
        }
    }
    __syncthreads();

    // --- main GEMM: [32 tok] x [512 outs], K=768, double-buffered chunks of 8 ---
    const int ng = tid & 63, mg = tid >> 6;
    const int j0 = ng * 8, t0 = mg * 8;
    const int arow0 = t0 + ((j0 < 384) ? 0 : 32);  // h rows at [0,32), ex rows at [32,64)

    float acc[8][8] = {};
    float4 wreg[4];
    float4 areg;

    load_w_regs(wcat, 0, tid, wreg);
    areg = load_a_reg(h, ex, tok0, 0, tid);
    store_w_lds(F, tid, wreg);
    store_a_lds(F + 8192, tid, areg);
    __syncthreads();

    int cur = 0;
    for (int c = 0; c < NCH; c++) {
        if (c < NCH - 1) {
            load_w_regs(wcat, c + 1, tid, wreg);
            areg = load_a_reg(h, ex, tok0, c + 1, tid);
        }
        {
            const float* wb = F + cur * 4096;
            const float* ab = F + 8192 + cur * 512 + arow0;
#pragma unroll
            for (int kk = 0; kk < KC; kk++) {
                float4 a0v = *(const float4*)(ab + kk * 64);
                float4 a1v = *(const float4*)(ab + kk * 64 + 4);
                const float* wr = wb + kk * 512 + j0;
                float4 w0v = *(const float4*)(wr);
                float4 w1v = *(const float4*)(wr + 4);
                float av[8] = {a0v.x, a0v.y, a0v.z, a0v.w, a1v.x, a1v.y, a1v.z, a1v.w};
                float wv[8] = {w0v.x, w0v.y, w0v.z, w0v.w, w1v.x, w1v.y, w1v.z, w1v.w};
#pragma unroll
                for (int i = 0; i < 8; i++)
#pragma unroll
                    for (int j = 0; j < 8; j++)
                        acc[i][j] = fmaf(av[i], wv[j], acc[i][j]);
            }
        }
        if (c < NCH - 1) {
            store_w_lds(F + (cur ^ 1) * 4096, tid, wreg);
            store_a_lds(F + 8192 + (cur ^ 1) * 512, tid, areg);
        }
        __syncthreads();
        cur ^= 1;
    }

    // --- epilogue part 1: a1 = silu(acc+b1); c1 partial (P-side with LN scalars) ---
    float* a1 = F;  // staging region dead
    if (j0 < 256) {
#pragma unroll
        for (int j = 0; j < 8; j++) {
            float b = bb1[j0 + j];
#pragma unroll
            for (int i = 0; i < 8; i++)
                a1[(t0 + i) * 256 + j0 + j] = silu_f(acc[i][j] + b);
        }
    } else if (j0 < 384) {
        int jj0 = j0 - 256;
#pragma unroll
        for (int j = 0; j < 8; j++) {
            float ga = gA[jj0 + j], cb = cbias[jj0 + j];
            float w1 = v1w[jj0 + j], w2 = v2w[jj0 + j], w3 = v3w[jj0 + j];
#pragma unroll
            for (int i = 0; i < 8; i++) {
                const float* st = stats + (t0 + i) * 8;
                float m = st[0], istd = st[1], mll = st[2], sll = st[3], dmu = st[4];
                c1[(t0 + i) * 128 + jj0 + j] =
                    istd * acc[i][j] - istd * m * ga + mll * w1 + sll * w2 + dmu * w3 + cb;
            }
        }
    }
    __syncthreads();
    // Q-side add + silu
    if (j0 >= 384) {
        int jj0 = j0 - 384;
#pragma unroll
        for (int j = 0; j < 8; j++)
#pragma unroll
            for (int i = 0; i < 8; i++) {
                float x = c1[(t0 + i) * 128 + jj0 + j] + acc[i][j];
                c1[(t0 + i) * 128 + jj0 + j] = silu_f(x);
            }
    }
    __syncthreads();

    // --- GEMM1b: base = a1 @ base_w2^T + b2  (32x49, K=256) ---
    for (int o = tid; o < TT * 49; o += 256) {
        int t = o / 49, s = o - t * 49;
        const float* ar = a1 + t * 256;
        const float* wr = bw2 + s * 256;
        float accv = bb2[s];
        for (int k = 0; k < 256; k += 4) {
            float4 av = *(const float4*)(ar + k);
            float4 wv = *(const float4*)(wr + k);
            accv += av.x * wv.x + av.y * wv.y + av.z * wv.z + av.w * wv.w;
        }
        basebuf[o] = accv;
    }
    __syncthreads();

    // --- GEMM2b: c = c1 @ mlp_w2^T + b2  (32x128, K=128) -> cbuf (overlays a1) ---
    float* cbuf = F;  // stride 132
    {
        int j = tid & 127, tg = tid >> 7;
        float accv[16];
#pragma unroll
        for (int tt = 0; tt < 16; tt++) accv[tt] = 0.f;
        const float* wr = mw2 + (size_t)j * 128;
        const float* cr = c1 + tg * 16 * 128;
        for (int k = 0; k < 128; k += 4) {
            float4 wv = *(const float4*)(wr + k);
#pragma unroll
            for (int tt = 0; tt < 16; tt++) {
                float4 cv = *(const float4*)(cr + tt * 128 + k);
                accv[tt] += cv.x * wv.x + cv.y * wv.y + cv.z * wv.z + cv.w * wv.w;
            }
        }
        float b = mb2[j];
        __syncthreads();  // ensure all a1 reads (GEMM1b) done before overlay write
#pragma unroll
        for (int tt = 0; tt < 16; tt++) cbuf[(tg * 16 + tt) * 132 + j] = accv[tt] + b;
    }
    __syncthreads();

    // --- mode logits + softmax(4) -> alpha; write alpha to out ---
    if (tid < 128) {
        int t = tid >> 2, m = tid & 3;
        const float* cr = cbuf + t * 132;
        float e = c4_s[m];
        for (int k = 0; k < 128; k++) e += cr[k] * cheff_s[k * 4 + m];
        float mx = fmaxf(e, __shfl_xor(e, 1));
        mx = fmaxf(mx, __shfl_xor(mx, 2));
        float ev = expf(e - mx);
        float sum = ev + __shfl_xor(ev, 1);
        sum += __shfl_xor(sum, 2);
        float al = ev / sum;
        alpha_s[t * 4 + m] = al;
        out[ALPHA_OFF + (size_t)(tok0 + t) * 4 + m] = al;
    }
    __syncthreads();

    // --- K: masked stage-graph softmax over rows of 7 ---
    if (tid < TT * 7) {
        int t = tid / 7, i = tid - t * 7;
        const float* al = alpha_s + t * 4;
        float sb[7];
#pragma unroll
        for (int s = 0; s < 7; s++)
            sb[s] = al[0] * msw_s[s * 4 + 0] + al[1] * msw_s[s * 4 + 1] +
                    al[2] * msw_s[s * 4 + 2] + al[3] * msw_s[s * 4 + 3];
        const float* br = basebuf + t * 49 + i * 7;
        const int* mrow = sg_s + i * 7;
        float vals[7];
        float mx = -1e30f;
#pragma unroll
        for (int j = 0; j < 7; j++) {
            float vv = br[j] + sb[j];
            vals[j] = mrow[j] ? vv : -1e30f;
            mx = fmaxf(mx, vals[j]);
        }
        float e[7], sum = 0.f;
#pragma unroll
        for (int j = 0; j < 7; j++) {
            e[j] = mrow[j] ? expf(vals[j] - mx) : 0.f;
            sum += e[j];
        }
        float inv = 1.f / sum;
        size_t off = (size_t)(tok0 + t) * 49 + i * 7;
#pragma unroll
        for (int j = 0; j < 7; j++) out[off + j] = e[j] * inv;
    }
}

// ---------------------------------------------------------------------------
extern "C" void kernel_launch(void* const* d_in, const int* in_sizes, int n_in,
                              void* d_out, int out_size, void* d_ws, size_t ws_size,
                              hipStream_t stream) {
    const float* h    = (const float*)d_in[0];
    const float* ex   = (const float*)d_in[1];
    const float* lam  = (const float*)d_in[2];
    const float* mup  = (const float*)d_in[3];
    const float* bw1  = (const float*)d_in[4];
    const float* bb1  = (const float*)d_in[5];
    const float* bw2  = (const float*)d_in[6];
    const float* bb2  = (const float*)d_in[7];
    const float* lng  = (const float*)d_in[8];
    const float* lnb  = (const float*)d_in[9];
    const float* mw1  = (const float*)d_in[10];
    const float* mb1  = (const float*)d_in[11];
    const float* mw2  = (const float*)d_in[12];
    const float* mb2  = (const float*)d_in[13];
    const float* pe   = (const float*)d_in[14];
    const float* chw  = (const float*)d_in[15];
    const float* chb  = (const float*)d_in[16];
    const float* phw  = (const float*)d_in[17];
    const float* phb  = (const float*)d_in[18];
    const float* bil  = (const float*)d_in[19];
    const float* mob  = (const float*)d_in[20];
    const float* msw  = (const float*)d_in[21];
    const int*   sg   = (const int*)d_in[22];
    const int*   pidx = (const int*)d_in[23];
    float* out = (float*)d_out;
    float* ws = (float*)d_ws;

    float* wcat  = ws + WS_WCAT;
    float* gA    = ws + WS_GA;
    float* cbias = ws + WS_CBIAS;
    float* v1    = ws + WS_V1;
    float* v2    = ws + WS_V2;
    float* v3    = ws + WS_V3;
    float* cheff = ws + WS_CHEFF;
    float* c4    = ws + WS_C4;

    hipLaunchKernelGGL(k_prep_wcat, dim3(1536), dim3(256), 0, stream, bw1, mw1, lng, wcat);
    hipLaunchKernelGGL(k_prep_small, dim3(1), dim3(256), 0, stream, mw1, mb1, lng, lnb, pe,
                       chw, chb, phw, phb, bil, mob, pidx, gA, cbias, v1, v2, v3, cheff, c4);
    hipLaunchKernelGGL(k_main, dim3(NT / TT), dim3(256), 0, stream, h, ex, lam, mup, bb1, bw2,
                       bb2, mw2, mb2, msw, sg, wcat, gA, cbias, v1, v2, v3, cheff, c4, out);
}

// Round 3
// 732.770 us; speedup vs baseline: 1.0538x; 1.0538x over previous
//
#include <hip/hip_runtime.h>
#include <cstdint>
#include <cstddef>

// ---------------------------------------------------------------------------
// Problem constants
// ---------------------------------------------------------------------------
#define NT      16384      // B*T tokens
#define DIM     768
#define TT      32         // tokens per block
#define KC      8          // K-chunk
#define NCH     (DIM/KC)   // 96 chunks
#define ALPHA_OFF 802816   // NT*49

// ws layout (floats)
#define WS_WCAT   0          // 768*512 = 393216
#define WS_GA     393216     // 128
#define WS_CBIAS  393344     // 128
#define WS_V1     393472     // 128
#define WS_V2     393600     // 128
#define WS_V3     393728     // 128
#define WS_CHEFF  393856     // 512 (transposed [k][m])
#define WS_C4     394368     // 4

__device__ __forceinline__ float silu_f(float x) { return x / (1.0f + expf(-x)); }

// ---------------------------------------------------------------------------
// Fused prep kernel, 97 blocks x 256 threads.
// Blocks 0..95: 64x64 tile transpose building wcat[k][j], k<768, j<512
//   j <  256 : base_w1[j][k]
//   j <  384 : mlp_w1[j-256][k] * ln_g[k]     (LN-scale folded in)
//   else     : mlp_w1[j-384][768+k]
// Block 96: small precomputes (gA, cbias, v1..v3, cheff_t, c4).
// ---------------------------------------------------------------------------
__global__ void k_prep(const float* __restrict__ bw1, const float* __restrict__ mw1,
                       const float* __restrict__ g, const float* __restrict__ mb1,
                       const float* __restrict__ lnb, const float* __restrict__ pe,
                       const float* __restrict__ chw, const float* __restrict__ chb,
                       const float* __restrict__ phw, const float* __restrict__ phb,
                       const float* __restrict__ bil, const float* __restrict__ mob,
                       const int* __restrict__ pidxp, float* __restrict__ wcat,
                       float* __restrict__ gA, float* __restrict__ cbias,
                       float* __restrict__ v1, float* __restrict__ v2,
                       float* __restrict__ v3, float* __restrict__ cheff_t,
                       float* __restrict__ c4) {
    __shared__ float tilebuf[64][65];
    __shared__ float u[32];
    int tid = threadIdx.x;

    if (blockIdx.x == 96) {
        // ---- small precomputes ----
        int pidx = *pidxp;
        if (tid < 32) u[tid] = pe[pidx * 32 + tid];
        __syncthreads();
        {
            int j = tid >> 1, half = tid & 1;
            const float* row = mw1 + (size_t)j * 1540 + half * 384;
            const float* gp = g + half * 384;
            const float* bp = lnb + half * 384;
            float sg_ = 0.f, sb_ = 0.f;
            for (int k = 0; k < 384; k += 4) {
                float4 rv = *(const float4*)(row + k);
                float4 gv = *(const float4*)(gp + k);
                float4 bv = *(const float4*)(bp + k);
                sg_ += rv.x * gv.x + rv.y * gv.y + rv.z * gv.z + rv.w * gv.w;
                sb_ += rv.x * bv.x + rv.y * bv.y + rv.z * bv.z + rv.w * bv.w;
            }
            sg_ += __shfl_xor(sg_, 1);
            sb_ += __shfl_xor(sb_, 1);
            if (half == 0) {
                const float* rowf = mw1 + (size_t)j * 1540;
                float pf = (float)pidx * (1.0f / 11.0f);
                gA[j] = sg_;
                v1[j] = rowf[1536];
                v2[j] = rowf[1537];
                v3[j] = rowf[1538];
                cbias[j] = sb_ + pf * rowf[1539] + mb1[j];
            }
        }
        for (int idx = tid; idx < 512; idx += 256) {
            int k = idx >> 2, m = idx & 3;
            float s = chw[m * 128 + k];
            for (int kk = 0; kk < 32; kk++) s += u[kk] * bil[(size_t)(m * 32 + kk) * 128 + k];
            cheff_t[k * 4 + m] = s;
        }
        if (tid < 4) {
            float s = chb[tid] + phb[tid] + mob[tid];
            for (int kk = 0; kk < 32; kk++) s += u[kk] * phw[tid * 32 + kk];
            c4[tid] = s;
        }
        return;
    }

    // ---- tile transpose: tile (kt, jt) covers k0..k0+63, j0..j0+63 ----
    int jt = blockIdx.x & 7, kt = blockIdx.x >> 3;
    int j0 = jt * 64, k0 = kt * 64;

    {   // coalesced read: thread (jl, kc) reads 16 consecutive k of row j0+jl
        int jl = tid >> 2, kc = (tid & 3) * 16;
        int j = j0 + jl;
        const float* src;
        if (j0 < 256)      src = bw1 + (size_t)j * DIM + k0;
        else if (j0 < 384) src = mw1 + (size_t)(j - 256) * 1540 + k0;
        else               src = mw1 + (size_t)(j - 384) * 1540 + 768 + k0;
#pragma unroll
        for (int q = 0; q < 16; q += 4) {
            float4 v = *(const float4*)(src + kc + q);
            tilebuf[jl][kc + q + 0] = v.x;
            tilebuf[jl][kc + q + 1] = v.y;
            tilebuf[jl][kc + q + 2] = v.z;
            tilebuf[jl][kc + q + 3] = v.w;
        }
    }
    __syncthreads();
    {   // coalesced write: thread (kl, jc) writes 16 consecutive j of row k0+kl
        int kl = tid >> 2, jc = (tid & 3) * 16;
        int k = k0 + kl;
        float scale = (j0 >= 256 && j0 < 384) ? g[k] : 1.0f;
        float* dst = wcat + (size_t)k * 512 + j0 + jc;
#pragma unroll
        for (int q = 0; q < 16; q += 4) {
            float4 v;
            v.x = tilebuf[jc + q + 0][kl] * scale;
            v.y = tilebuf[jc + q + 1][kl] * scale;
            v.z = tilebuf[jc + q + 2][kl] * scale;
            v.w = tilebuf[jc + q + 3][kl] * scale;
            *(float4*)(dst + q) = v;
        }
    }
}

// ---------------------------------------------------------------------------
// Main fused kernel. 512 blocks x 256 threads, 32 tokens per block.
// Thread (ng=tid&63, mg=tid>>6) owns tokens t0..t0+7 (t0=mg*8) and output
// column groups {4ng..4ng+3} (base-W1, from h) and {256+4ng..+3} (ctrl:
// lanes 0-31 -> Wa' cols 4ng   [P-side, from h],
// lanes 32-63 -> Wb  cols 4ng-128 [Q-side, from emb_x]).
// Both W LDS reads are lane-consecutive ds_read_b128 -> conflict-free.
// Shared layout (floats), total 15872 floats = 63.5 KB:
//   [0,9216)      : union { staging: wbuf[2][4096] @0, abuf[2][512] @8192 }
//                         { a1[32][256] @0 }  { cbuf[32][132] @0 (after a1 dead) }
//   [9216,13312)  : c1[32][128]
//   [13312,14880) : basebuf[32][49]
//   [14880,15136) : stats[32][8]
//   [15136,15648) : cheff_s[512]
//   [15648,15776) : alpha_s[32][4]
//   [15776,15780) : c4_s
//   [15780,15808) : msw_s[28]
//   [15808,15857) : sg_s[49] (ints)
// ---------------------------------------------------------------------------
__device__ __forceinline__ void load_w_regs(const float* __restrict__ wcat, int c, int tid,
                                            float4 w[4]) {
    const float* s = wcat + (size_t)c * 4096 + tid * 4;
    w[0] = *(const float4*)(s);
    w[1] = *(const float4*)(s + 1024);
    w[2] = *(const float4*)(s + 2048);
    w[3] = *(const float4*)(s + 3072);
}
__device__ __forceinline__ void store_w_lds(float* wb, int tid, const float4 w[4]) {
    *(float4*)(wb + tid * 4) = w[0];
    *(float4*)(wb + 1024 + tid * 4) = w[1];
    *(float4*)(wb + 2048 + tid * 4) = w[2];
    *(float4*)(wb + 3072 + tid * 4) = w[3];
}
__device__ __forceinline__ float4 load_a_reg(const float* __restrict__ h,
                                             const float* __restrict__ ex, int tok0, int c,
                                             int tid) {
    if (tid < 128) {
        int t = (tid & 63) >> 1, half = tid & 1;
        const float* src = (tid < 64 ? h : ex) + (size_t)(tok0 + t) * DIM + c * KC + half * 4;
        return *(const float4*)src;
    }
    return make_float4(0.f, 0.f, 0.f, 0.f);
}
__device__ __forceinline__ void store_a_lds(float* ab, int tid, float4 a) {
    if (tid < 128) {
        int t = (tid & 63) >> 1, half = tid & 1, asel = (tid < 64) ? 0 : 32;
        float* d = ab + (half * 4) * 64 + asel + t;  // row stride 64: [k][t]
        d[0] = a.x; d[64] = a.y; d[128] = a.z; d[192] = a.w;
    }
}

__launch_bounds__(256, 2)
__global__ void k_main(const float* __restrict__ h, const float* __restrict__ ex,
                       const float* __restrict__ lam, const float* __restrict__ mup,
                       const float* __restrict__ bb1, const float* __restrict__ bw2,
                       const float* __restrict__ bb2, const float* __restrict__ mw2,
                       const float* __restrict__ mb2, const float* __restrict__ msw,
                       const int* __restrict__ sg, const float* __restrict__ wcat,
                       const float* __restrict__ gA, const float* __restrict__ cbias,
                       const float* __restrict__ v1w, const float* __restrict__ v2w,
                       const float* __restrict__ v3w, const float* __restrict__ cheff_t,
                       const float* __restrict__ c4, float* __restrict__ out) {
    __shared__ float F[15872];
    float* c1      = F + 9216;
    float* basebuf = F + 13312;
    float* stats   = F + 14880;
    float* cheff_s = F + 15136;
    float* alpha_s = F + 15648;
    float* c4_s    = F + 15776;
    float* msw_s   = F + 15780;
    int*   sg_s    = (int*)(F + 15808);

    const int tid = threadIdx.x;
    const int bid = blockIdx.x;
    const int tok0 = bid * TT;

    // --- small constant preloads ---
    if (tid < 49) sg_s[tid] = sg[tid];
    if (tid >= 64 && tid < 92) msw_s[tid - 64] = msw[tid - 64];
    if (tid >= 96 && tid < 100) c4_s[tid - 96] = c4[tid - 96];
    for (int i = tid; i < 512; i += 256) cheff_s[i] = cheff_t[i];

    // --- stats pass: 8 threads per token ---
    {
        int t = tid >> 3, r = tid & 7;
        const float* hp = h + (size_t)(tok0 + t) * DIM;
        const float* lp = lam + (size_t)(tok0 + t) * DIM;
        const float* mp = mup + (size_t)(tok0 + t) * DIM;
        float sh = 0.f, sh2 = 0.f, sll = 0.f, sll2 = 0.f, sd = 0.f;
        for (int i = 0; i < 24; i++) {
            int k0 = i * 32 + r * 4;
            float4 hv = *(const float4*)(hp + k0);
            float4 lv = *(const float4*)(lp + k0);
            float4 mv = *(const float4*)(mp + k0);
#pragma unroll
            for (int e = 0; e < 4; e++) {
                float hx = (&hv.x)[e];
                float lx = fmaxf((&lv.x)[e], 1e-6f);
                float mx = (&mv.x)[e];
                sh += hx; sh2 += hx * hx;
                float ll = logf(lx);
                sll += ll; sll2 += ll * ll;
                float dd = hx - mx; sd += dd * dd;
            }
        }
#pragma unroll
        for (int off = 1; off < 8; off <<= 1) {
            sh += __shfl_xor(sh, off);  sh2 += __shfl_xor(sh2, off);
            sll += __shfl_xor(sll, off); sll2 += __shfl_xor(sll2, off);
            sd += __shfl_xor(sd, off);
        }
        if (r == 0) {
            float m = sh * (1.f / 768.f);
            float var = sh2 * (1.f / 768.f) - m * m;
            float istd = rsqrtf(var + 1e-5f);
            float mll = sll * (1.f / 768.f);
            float vll = (sll2 - 768.f * mll * mll) * (1.f / 767.f);
            float sstd = fmaxf(sqrtf(fmaxf(vll, 0.f)), 1e-6f);
            float dmu = sqrtf(sd * (1.f / 768.f) + 1e-8f);
            float* st = stats + t * 8;
            st[0] = m; st[1] = istd; st[2] = mll; st[3] = sstd; st[4] = dmu;
        }
    }
    __syncthreads();

    // --- main GEMM: [32 tok] x [512 outs], K=768, double-buffered chunks of 8 ---
    const int ng = tid & 63, mg = tid >> 6;
    const int jlo = ng * 4;               // base-W1 column group
    const int t0 = mg * 8;
    const int asel = (ng < 32) ? t0 : (32 + t0);  // ctrl-group A source (h | ex)

    float accL[8][4] = {};  // tokens x base cols [4ng..4ng+3]
    float accH[8][4] = {};  // tokens x ctrl cols [256+4ng..+3]
    float4 wreg[4];
    float4 areg;

    load_w_regs(wcat, 0, tid, wreg);
    areg = load_a_reg(h, ex, tok0, 0, tid);
    store_w_lds(F, tid, wreg);
    store_a_lds(F + 8192, tid, areg);
    __syncthreads();

    int cur = 0;
    for (int c = 0; c < NCH; c++) {
        if (c < NCH - 1) {
            load_w_regs(wcat, c + 1, tid, wreg);
            areg = load_a_reg(h, ex, tok0, c + 1, tid);
        }
        {
            const float* wb = F + cur * 4096;
            const float* ab = F + 8192 + cur * 512;
#pragma unroll
            for (int kk = 0; kk < KC; kk++) {
                const float* ar = ab + kk * 64;
                float4 h0 = *(const float4*)(ar + t0);
                float4 h1 = *(const float4*)(ar + t0 + 4);
                float4 s0 = *(const float4*)(ar + asel);
                float4 s1 = *(const float4*)(ar + asel + 4);
                const float* wr = wb + kk * 512 + jlo;
                float4 wl = *(const float4*)(wr);
                float4 wh = *(const float4*)(wr + 256);
                float ah[8] = {h0.x, h0.y, h0.z, h0.w, h1.x, h1.y, h1.z, h1.w};
                float as[8] = {s0.x, s0.y, s0.z, s0.w, s1.x, s1.y, s1.z, s1.w};
                float wlv[4] = {wl.x, wl.y, wl.z, wl.w};
                float whv[4] = {wh.x, wh.y, wh.z, wh.w};
#pragma unroll
                for (int i = 0; i < 8; i++)
#pragma unroll
                    for (int j = 0; j < 4; j++) {
                        accL[i][j] = fmaf(ah[i], wlv[j], accL[i][j]);
                        accH[i][j] = fmaf(as[i], whv[j], accH[i][j]);
                    }
            }
        }
        if (c < NCH - 1) {
            store_w_lds(F + (cur ^ 1) * 4096, tid, wreg);
            store_a_lds(F + 8192 + (cur ^ 1) * 512, tid, areg);
        }
        __syncthreads();
        cur ^= 1;
    }

    // --- epilogue part 1: a1 = silu(accL+b1); c1 P-side (lanes 0-31, LN scalars) ---
    float* a1 = F;  // staging region dead
    {
        float4 b4 = *(const float4*)(bb1 + jlo);
#pragma unroll
        for (int i = 0; i < 8; i++) {
            float4 v;
            v.x = silu_f(accL[i][0] + b4.x);
            v.y = silu_f(accL[i][1] + b4.y);
            v.z = silu_f(accL[i][2] + b4.z);
            v.w = silu_f(accL[i][3] + b4.w);
            *(float4*)(a1 + (t0 + i) * 256 + jlo) = v;
        }
    }
    if (ng < 32) {
        int jj0 = jlo;  // 4ng in [0,128)
        float4 ga4 = *(const float4*)(gA + jj0);
        float4 cb4 = *(const float4*)(cbias + jj0);
        float4 w14 = *(const float4*)(v1w + jj0);
        float4 w24 = *(const float4*)(v2w + jj0);
        float4 w34 = *(const float4*)(v3w + jj0);
#pragma unroll
        for (int i = 0; i < 8; i++) {
            const float* st = stats + (t0 + i) * 8;
            float m = st[0], istd = st[1], mll = st[2], sll = st[3], dmu = st[4];
            float nim = -istd * m;
            float4 r;
            r.x = istd * accH[i][0] + nim * ga4.x + mll * w14.x + sll * w24.x + dmu * w34.x + cb4.x;
            r.y = istd * accH[i][1] + nim * ga4.y + mll * w14.y + sll * w24.y + dmu * w34.y + cb4.y;
            r.z = istd * accH[i][2] + nim * ga4.z + mll * w14.z + sll * w24.z + dmu * w34.z + cb4.z;
            r.w = istd * accH[i][3] + nim * ga4.w + mll * w14.w + sll * w24.w + dmu * w34.w + cb4.w;
            *(float4*)(c1 + (t0 + i) * 128 + jj0) = r;
        }
    }
    __syncthreads();
    // Q-side add + silu (lanes 32-63)
    if (ng >= 32) {
        int jj0 = jlo - 128;  // in [0,128)
#pragma unroll
        for (int i = 0; i < 8; i++) {
            float* cp = c1 + (t0 + i) * 128 + jj0;
            float4 cv = *(const float4*)cp;
            cv.x = silu_f(cv.x + accH[i][0]);
            cv.y = silu_f(cv.y + accH[i][1]);
            cv.z = silu_f(cv.z + accH[i][2]);
            cv.w = silu_f(cv.w + accH[i][3]);
            *(float4*)cp = cv;
        }
    }
    __syncthreads();

    // --- GEMM1b: base = a1 @ base_w2^T + b2  (32x49, K=256) ---
    for (int o = tid; o < TT * 49; o += 256) {
        int t = o / 49, s = o - t * 49;
        const float* ar = a1 + t * 256;
        const float* wr = bw2 + s * 256;
        float accv = bb2[s];
        for (int k = 0; k < 256; k += 4) {
            float4 av = *(const float4*)(ar + k);
            float4 wv = *(const float4*)(wr + k);
            accv += av.x * wv.x + av.y * wv.y + av.z * wv.z + av.w * wv.w;
        }
        basebuf[o] = accv;
    }
    __syncthreads();

    // --- GEMM2b: c = c1 @ mlp_w2^T + b2  (32x128, K=128) -> cbuf (overlays a1) ---
    float* cbuf = F;  // stride 132
    {
        int j = tid & 127, tg = tid >> 7;
        float accv[16];
#pragma unroll
        for (int tt = 0; tt < 16; tt++) accv[tt] = 0.f;
        const float* wr = mw2 + (size_t)j * 128;
        const float* cr = c1 + tg * 16 * 128;
        for (int k = 0; k < 128; k += 4) {
            float4 wv = *(const float4*)(wr + k);
#pragma unroll
            for (int tt = 0; tt < 16; tt++) {
                float4 cv = *(const float4*)(cr + tt * 128 + k);
                accv[tt] += cv.x * wv.x + cv.y * wv.y + cv.z * wv.z + cv.w * wv.w;
            }
        }
        float b = mb2[j];
        __syncthreads();  // ensure all a1 reads (GEMM1b) done before overlay write
#pragma unroll
        for (int tt = 0; tt < 16; tt++) cbuf[(tg * 16 + tt) * 132 + j] = accv[tt] + b;
    }
    __syncthreads();

    // --- mode logits + softmax(4) -> alpha; write alpha to out ---
    if (tid < 128) {
        int t = tid >> 2, m = tid & 3;
        const float* cr = cbuf + t * 132;
        float e = c4_s[m];
        for (int k = 0; k < 128; k++) e += cr[k] * cheff_s[k * 4 + m];
        float mx = fmaxf(e, __shfl_xor(e, 1));
        mx = fmaxf(mx, __shfl_xor(mx, 2));
        float ev = expf(e - mx);
        float sum = ev + __shfl_xor(ev, 1);
        sum += __shfl_xor(sum, 2);
        float al = ev / sum;
        alpha_s[t * 4 + m] = al;
        out[ALPHA_OFF + (size_t)(tok0 + t) * 4 + m] = al;
    }
    __syncthreads();

    // --- K: masked stage-graph softmax over rows of 7 ---
    if (tid < TT * 7) {
        int t = tid / 7, i = tid - t * 7;
        const float* al = alpha_s + t * 4;
        float sb[7];
#pragma unroll
        for (int s = 0; s < 7; s++)
            sb[s] = al[0] * msw_s[s * 4 + 0] + al[1] * msw_s[s * 4 + 1] +
                    al[2] * msw_s[s * 4 + 2] + al[3] * msw_s[s * 4 + 3];
        const float* br = basebuf + t * 49 + i * 7;
        const int* mrow = sg_s + i * 7;
        float vals[7];
        float mx = -1e30f;
#pragma unroll
        for (int j = 0; j < 7; j++) {
            float vv = br[j] + sb[j];
            vals[j] = mrow[j] ? vv : -1e30f;
            mx = fmaxf(mx, vals[j]);
        }
        float e[7], sum = 0.f;
#pragma unroll
        for (int j = 0; j < 7; j++) {
            e[j] = mrow[j] ? expf(vals[j] - mx) : 0.f;
            sum += e[j];
        }
        float inv = 1.f / sum;
        size_t off = (size_t)(tok0 + t) * 49 + i * 7;
#pragma unroll
        for (int j = 0; j < 7; j++) out[off + j] = e[j] * inv;
    }
}

// ---------------------------------------------------------------------------
extern "C" void kernel_launch(void* const* d_in, const int* in_sizes, int n_in,
                              void* d_out, int out_size, void* d_ws, size_t ws_size,
                              hipStream_t stream) {
    const float* h    = (const float*)d_in[0];
    const float* ex   = (const float*)d_in[1];
    const float* lam  = (const float*)d_in[2];
    const float* mup  = (const float*)d_in[3];
    const float* bw1  = (const float*)d_in[4];
    const float* bb1  = (const float*)d_in[5];
    const float* bw2  = (const float*)d_in[6];
    const float* bb2  = (const float*)d_in[7];
    const float* lng  = (const float*)d_in[8];
    const float* lnb  = (const float*)d_in[9];
    const float* mw1  = (const float*)d_in[10];
    const float* mb1  = (const float*)d_in[11];
    const float* mw2  = (const float*)d_in[12];
    const float* mb2  = (const float*)d_in[13];
    const float* pe   = (const float*)d_in[14];
    const float* chw  = (const float*)d_in[15];
    const float* chb  = (const float*)d_in[16];
    const float* phw  = (const float*)d_in[17];
    const float* phb  = (const float*)d_in[18];
    const float* bil  = (const float*)d_in[19];
    const float* mob  = (const float*)d_in[20];
    const float* msw  = (const float*)d_in[21];
    const int*   sg   = (const int*)d_in[22];
    const int*   pidx = (const int*)d_in[23];
    float* out = (float*)d_out;
    float* ws = (float*)d_ws;

    float* wcat  = ws + WS_WCAT;
    float* gA    = ws + WS_GA;
    float* cbias = ws + WS_CBIAS;
    float* v1    = ws + WS_V1;
    float* v2    = ws + WS_V2;
    float* v3    = ws + WS_V3;
    float* cheff = ws + WS_CHEFF;
    float* c4    = ws + WS_C4;

    hipLaunchKernelGGL(k_prep, dim3(97), dim3(256), 0, stream, bw1, mw1, lng, mb1, lnb, pe,
                       chw, chb, phw, phb, bil, mob, pidx, wcat, gA, cbias, v1, v2, v3,
                       cheff, c4);
    hipLaunchKernelGGL(k_main, dim3(NT / TT), dim3(256), 0, stream, h, ex, lam, mup, bb1, bw2,
                       bb2, mw2, mb2, msw, sg, wcat, gA, cbias, v1, v2, v3, cheff, c4, out);
}

// Round 5
// 534.490 us; speedup vs baseline: 1.4447x; 1.3710x over previous
//
#include <hip/hip_runtime.h>
#include <cstdint>
#include <cstddef>

// ---------------------------------------------------------------------------
// Problem constants
// ---------------------------------------------------------------------------
#define NT      16384      // B*T tokens
#define DIM     768
#define TT      32         // tokens per block
#define KC      8          // K-chunk
#define NCH     (DIM/KC)   // 96 chunks
#define ALPHA_OFF 802816   // NT*49

// ws layout (floats)
#define WS_WCAT   0          // 768*512 = 393216
#define WS_GA     393216     // 128
#define WS_CBIAS  393344     // 128
#define WS_V1     393472     // 128
#define WS_V2     393600     // 128
#define WS_V3     393728     // 128
#define WS_CHEFF  393856     // 512 (transposed [k][m])
#define WS_C4     394368     // 4

__device__ __forceinline__ float silu_f(float x) { return x / (1.0f + expf(-x)); }

// ---------------------------------------------------------------------------
// Fused prep kernel, 97 blocks x 256 threads.
// Blocks 0..95: 64x64 tile transpose building wcat[k][pos], k<768, PERMUTED
// columns: orig col j (g=j>>3, r=j&7) lives at
//   pos = (r<4) ? g*4+r : 256 + g*4 + (r-4)
// so that k_main thread ng's 8 cols {8ng..8ng+7} are two lane-consecutive
// float4 slots (4ng and 256+4ng) -> conflict-free ds_read_b128.
// Column sources:
//   j <  256 : base_w1[j][k]
//   j <  384 : mlp_w1[j-256][k] * ln_g[k]     (LN-scale folded in)
//   else     : mlp_w1[j-384][768+k]
// Block 96: small precomputes (gA, cbias, v1..v3, cheff_t, c4).
// ---------------------------------------------------------------------------
__global__ void k_prep(const float* __restrict__ bw1, const float* __restrict__ mw1,
                       const float* __restrict__ g, const float* __restrict__ mb1,
                       const float* __restrict__ lnb, const float* __restrict__ pe,
                       const float* __restrict__ chw, const float* __restrict__ chb,
                       const float* __restrict__ phw, const float* __restrict__ phb,
                       const float* __restrict__ bil, const float* __restrict__ mob,
                       const int* __restrict__ pidxp, float* __restrict__ wcat,
                       float* __restrict__ gA, float* __restrict__ cbias,
                       float* __restrict__ v1, float* __restrict__ v2,
                       float* __restrict__ v3, float* __restrict__ cheff_t,
                       float* __restrict__ c4) {
    __shared__ float tilebuf[64][65];
    __shared__ float u[32];
    int tid = threadIdx.x;

    if (blockIdx.x == 96) {
        // ---- small precomputes ----
        int pidx = *pidxp;
        if (tid < 32) u[tid] = pe[pidx * 32 + tid];
        __syncthreads();
        {
            int j = tid >> 1, half = tid & 1;
            const float* row = mw1 + (size_t)j * 1540 + half * 384;
            const float* gp = g + half * 384;
            const float* bp = lnb + half * 384;
            float sg_ = 0.f, sb_ = 0.f;
            for (int k = 0; k < 384; k += 4) {
                float4 rv = *(const float4*)(row + k);
                float4 gv = *(const float4*)(gp + k);
                float4 bv = *(const float4*)(bp + k);
                sg_ += rv.x * gv.x + rv.y * gv.y + rv.z * gv.z + rv.w * gv.w;
                sb_ += rv.x * bv.x + rv.y * bv.y + rv.z * bv.z + rv.w * bv.w;
            }
            sg_ += __shfl_xor(sg_, 1);
            sb_ += __shfl_xor(sb_, 1);
            if (half == 0) {
                const float* rowf = mw1 + (size_t)j * 1540;
                float pf = (float)pidx * (1.0f / 11.0f);
                gA[j] = sg_;
                v1[j] = rowf[1536];
                v2[j] = rowf[1537];
                v3[j] = rowf[1538];
                cbias[j] = sb_ + pf * rowf[1539] + mb1[j];
            }
        }
        for (int idx = tid; idx < 512; idx += 256) {
            int k = idx >> 2, m = idx & 3;
            float s = chw[m * 128 + k];
            for (int kk = 0; kk < 32; kk++) s += u[kk] * bil[(size_t)(m * 32 + kk) * 128 + k];
            cheff_t[k * 4 + m] = s;
        }
        if (tid < 4) {
            float s = chb[tid] + phb[tid] + mob[tid];
            for (int kk = 0; kk < 32; kk++) s += u[kk] * phw[tid * 32 + kk];
            c4[tid] = s;
        }
        return;
    }

    // ---- tile transpose: tile (kt, jt) covers k0..k0+63, j0..j0+63 ----
    int jt = blockIdx.x & 7, kt = blockIdx.x >> 3;
    int j0 = jt * 64, k0 = kt * 64;

    {   // coalesced read: thread (jl, kc) reads 16 consecutive k of row j0+jl
        int jl = tid >> 2, kc = (tid & 3) * 16;
        int j = j0 + jl;
        const float* src;
        if (j0 < 256)      src = bw1 + (size_t)j * DIM + k0;
        else if (j0 < 384) src = mw1 + (size_t)(j - 256) * 1540 + k0;
        else               src = mw1 + (size_t)(j - 384) * 1540 + 768 + k0;
#pragma unroll
        for (int q = 0; q < 16; q += 4) {
            float4 v = *(const float4*)(src + kc + q);
            tilebuf[jl][kc + q + 0] = v.x;
            tilebuf[jl][kc + q + 1] = v.y;
            tilebuf[jl][kc + q + 2] = v.z;
            tilebuf[jl][kc + q + 3] = v.w;
        }
    }
    __syncthreads();
    {   // permuted write: thread (kl, jc) handles orig cols j0+jc .. j0+jc+15
        int kl = tid >> 2, jc = (tid & 3) * 16;
        int k = k0 + kl;
        float scale = (j0 >= 256 && j0 < 384) ? g[k] : 1.0f;
        int g0 = (j0 + jc) >> 3;  // even group index
        float* dstA = wcat + (size_t)k * 512 + g0 * 4;
        float* dstB = dstA + 256;
        float4 A1, A2, B1, B2;
        A1.x = tilebuf[jc + 0][kl] * scale;  A1.y = tilebuf[jc + 1][kl] * scale;
        A1.z = tilebuf[jc + 2][kl] * scale;  A1.w = tilebuf[jc + 3][kl] * scale;
        B1.x = tilebuf[jc + 4][kl] * scale;  B1.y = tilebuf[jc + 5][kl] * scale;
        B1.z = tilebuf[jc + 6][kl] * scale;  B1.w = tilebuf[jc + 7][kl] * scale;
        A2.x = tilebuf[jc + 8][kl] * scale;  A2.y = tilebuf[jc + 9][kl] * scale;
        A2.z = tilebuf[jc + 10][kl] * scale; A2.w = tilebuf[jc + 11][kl] * scale;
        B2.x = tilebuf[jc + 12][kl] * scale; B2.y = tilebuf[jc + 13][kl] * scale;
        B2.z = tilebuf[jc + 14][kl] * scale; B2.w = tilebuf[jc + 15][kl] * scale;
        *(float4*)(dstA) = A1;
        *(float4*)(dstA + 4) = A2;
        *(float4*)(dstB) = B1;
        *(float4*)(dstB + 4) = B2;
    }
}

// ---------------------------------------------------------------------------
// Main fused kernel. 512 blocks x 256 threads, 32 tokens per block.
// Thread (ng=tid&63, mg=tid>>6) owns tokens t0..t0+7 (t0=mg*8) and orig
// output cols {8ng..8ng+7}, which live at permuted LDS float4 slots 4ng and
// 256+4ng (lane-consecutive -> conflict-free). Single A-fragment per thread
// (h for ng<48, emb_x for ng>=48); inner loop = 4 ds_read_b128 + 64 FMA,
// register profile matches the proven spill-free round-1 kernel.
// Shared layout (floats), total 15872 floats = 63.5 KB:
//   [0,9216)      : union { staging: wbuf[2][4096] @0, abuf[2][512] @8192 }
//                         { a1[32][256] @0 }  { cbuf[32][132] @0 (after a1 dead) }
//   [9216,13312)  : c1[32][128]
//   [13312,14880) : basebuf[32][49]
//   [14880,15136) : stats[32][8]
//   [15136,15648) : cheff_s[512]
//   [15648,15776) : alpha_s[32][4]
//   [15776,15780) : c4_s
//   [15780,15808) : msw_s[28]
//   [15808,15857) : sg_s[49] (ints)
// ---------------------------------------------------------------------------
__device__ __forceinline__ void load_w_regs(const float* __restrict__ wcat, int c, int tid,
                                            float4 w[4]) {
    const float* s = wcat + (size_t)c * 4096 + tid * 4;
    w[0] = *(const float4*)(s);
    w[1] = *(const float4*)(s + 1024);
    w[2] = *(const float4*)(s + 2048);
    w[3] = *(const float4*)(s + 3072);
}
__device__ __forceinline__ void store_w_lds(float* wb, int tid, const float4 w[4]) {
    *(float4*)(wb + tid * 4) = w[0];
    *(float4*)(wb + 1024 + tid * 4) = w[1];
    *(float4*)(wb + 2048 + tid * 4) = w[2];
    *(float4*)(wb + 3072 + tid * 4) = w[3];
}
__device__ __forceinline__ float4 load_a_reg(const float* __restrict__ h,
                                             const float* __restrict__ ex, int tok0, int c,
                                             int tid) {
    if (tid < 128) {
        int t = (tid & 63) >> 1, half = tid & 1;
        const float* src = (tid < 64 ? h : ex) + (size_t)(tok0 + t) * DIM + c * KC + half * 4;
        return *(const float4*)src;
    }
    return make_float4(0.f, 0.f, 0.f, 0.f);
}
__device__ __forceinline__ void store_a_lds(float* ab, int tid, float4 a) {
    if (tid < 128) {
        int t = (tid & 63) >> 1, half = tid & 1, asel = (tid < 64) ? 0 : 32;
        float* d = ab + (half * 4) * 64 + asel + t;  // row stride 64: [k][t]
        d[0] = a.x; d[64] = a.y; d[128] = a.z; d[192] = a.w;
    }
}

__launch_bounds__(256, 2)
__global__ void k_main(const float* __restrict__ h, const float* __restrict__ ex,
                       const float* __restrict__ lam, const float* __restrict__ mup,
                       const float* __restrict__ bb1, const float* __restrict__ bw2,
                       const float* __restrict__ bb2, const float* __restrict__ mw2,
                       const float* __restrict__ mb2, const float* __restrict__ msw,
                       const int* __restrict__ sg, const float* __restrict__ wcat,
                       const float* __restrict__ gA, const float* __restrict__ cbias,
                       const float* __restrict__ v1w, const float* __restrict__ v2w,
                       const float* __restrict__ v3w, const float* __restrict__ cheff_t,
                       const float* __restrict__ c4, float* __restrict__ out) {
    __shared__ float F[15872];
    float* c1      = F + 9216;
    float* basebuf = F + 13312;
    float* stats   = F + 14880;
    float* cheff_s = F + 15136;
    float* alpha_s = F + 15648;
    float* c4_s    = F + 15776;
    float* msw_s   = F + 15780;
    int*   sg_s    = (int*)(F + 15808);

    const int tid = threadIdx.x;
    const int bid = blockIdx.x;
    const int tok0 = bid * TT;

    // --- small constant preloads ---
    if (tid < 49) sg_s[tid] = sg[tid];
    if (tid >= 64 && tid < 92) msw_s[tid - 64] = msw[tid - 64];
    if (tid >= 96 && tid < 100) c4_s[tid - 96] = c4[tid - 96];
    for (int i = tid; i < 512; i += 256) cheff_s[i] = cheff_t[i];

    // --- stats pass: 8 threads per token ---
    {
        int t = tid >> 3, r = tid & 7;
        const float* hp = h + (size_t)(tok0 + t) * DIM;
        const float* lp = lam + (size_t)(tok0 + t) * DIM;
        const float* mp = mup + (size_t)(tok0 + t) * DIM;
        float sh = 0.f, sh2 = 0.f, sll = 0.f, sll2 = 0.f, sd = 0.f;
        for (int i = 0; i < 24; i++) {
            int k0 = i * 32 + r * 4;
            float4 hv = *(const float4*)(hp + k0);
            float4 lv = *(const float4*)(lp + k0);
            float4 mv = *(const float4*)(mp + k0);
#pragma unroll
            for (int e = 0; e < 4; e++) {
                float hx = (&hv.x)[e];
                float lx = fmaxf((&lv.x)[e], 1e-6f);
                float mx = (&mv.x)[e];
                sh += hx; sh2 += hx * hx;
                float ll = logf(lx);
                sll += ll; sll2 += ll * ll;
                float dd = hx - mx; sd += dd * dd;
            }
        }
#pragma unroll
        for (int off = 1; off < 8; off <<= 1) {
            sh += __shfl_xor(sh, off);  sh2 += __shfl_xor(sh2, off);
            sll += __shfl_xor(sll, off); sll2 += __shfl_xor(sll2, off);
            sd += __shfl_xor(sd, off);
        }
        if (r == 0) {
            float m = sh * (1.f / 768.f);
            float var = sh2 * (1.f / 768.f) - m * m;
            float istd = rsqrtf(var + 1e-5f);
            float mll = sll * (1.f / 768.f);
            float vll = (sll2 - 768.f * mll * mll) * (1.f / 767.f);
            float sstd = fmaxf(sqrtf(fmaxf(vll, 0.f)), 1e-6f);
            float dmu = sqrtf(sd * (1.f / 768.f) + 1e-8f);
            float* st = stats + t * 8;
            st[0] = m; st[1] = istd; st[2] = mll; st[3] = sstd; st[4] = dmu;
        }
    }
    __syncthreads();

    // --- main GEMM: [32 tok] x [512 outs], K=768, double-buffered chunks of 8 ---
    const int ng = tid & 63, mg = tid >> 6;
    const int j0 = ng * 8, t0 = mg * 8;
    const int arow0 = t0 + ((ng < 48) ? 0 : 32);  // h rows at [0,32), ex rows at [32,64)

    float acc[8][8] = {};
    float4 wreg[4];
    float4 areg;

    load_w_regs(wcat, 0, tid, wreg);
    areg = load_a_reg(h, ex, tok0, 0, tid);
    store_w_lds(F, tid, wreg);
    store_a_lds(F + 8192, tid, areg);
    __syncthreads();

    int cur = 0;
    for (int c = 0; c < NCH; c++) {
        if (c < NCH - 1) {
            load_w_regs(wcat, c + 1, tid, wreg);
            areg = load_a_reg(h, ex, tok0, c + 1, tid);
        }
        {
            const float* wb = F + cur * 4096;
            const float* ab = F + 8192 + cur * 512 + arow0;
#pragma unroll
            for (int kk = 0; kk < KC; kk++) {
                float4 a0v = *(const float4*)(ab + kk * 64);
                float4 a1v = *(const float4*)(ab + kk * 64 + 4);
                const float* wr = wb + kk * 512 + ng * 4;
                float4 wl = *(const float4*)(wr);        // orig cols j0..j0+3
                float4 wh = *(const float4*)(wr + 256);  // orig cols j0+4..j0+7
                float av[8] = {a0v.x, a0v.y, a0v.z, a0v.w, a1v.x, a1v.y, a1v.z, a1v.w};
                float wv[8] = {wl.x, wl.y, wl.z, wl.w, wh.x, wh.y, wh.z, wh.w};
#pragma unroll
                for (int i = 0; i < 8; i++)
#pragma unroll
                    for (int j = 0; j < 8; j++)
                        acc[i][j] = fmaf(av[i], wv[j], acc[i][j]);
            }
        }
        if (c < NCH - 1) {
            store_w_lds(F + (cur ^ 1) * 4096, tid, wreg);
            store_a_lds(F + 8192 + (cur ^ 1) * 512, tid, areg);
        }
        __syncthreads();
        cur ^= 1;
    }

    // --- epilogue part 1: a1 = silu(acc+b1) [ng<32]; c1 P-side [ng in 32..47] ---
    float* a1 = F;  // staging region dead
    if (ng < 32) {
        float4 ba = *(const float4*)(bb1 + j0);
        float4 bb = *(const float4*)(bb1 + j0 + 4);
#pragma unroll
        for (int i = 0; i < 8; i++) {
            float4 v0, v1;
            v0.x = silu_f(acc[i][0] + ba.x);
            v0.y = silu_f(acc[i][1] + ba.y);
            v0.z = silu_f(acc[i][2] + ba.z);
            v0.w = silu_f(acc[i][3] + ba.w);
            v1.x = silu_f(acc[i][4] + bb.x);
            v1.y = silu_f(acc[i][5] + bb.y);
            v1.z = silu_f(acc[i][6] + bb.z);
            v1.w = silu_f(acc[i][7] + bb.w);
            *(float4*)(a1 + (t0 + i) * 256 + j0) = v0;
            *(float4*)(a1 + (t0 + i) * 256 + j0 + 4) = v1;
        }
    } else if (ng < 48) {
        int jj0 = j0 - 256;  // in [0,128), step 8
        float4 ga0 = *(const float4*)(gA + jj0),    ga1 = *(const float4*)(gA + jj0 + 4);
        float4 cb0 = *(const float4*)(cbias + jj0), cb1 = *(const float4*)(cbias + jj0 + 4);
        float4 w10 = *(const float4*)(v1w + jj0),   w11 = *(const float4*)(v1w + jj0 + 4);
        float4 w20 = *(const float4*)(v2w + jj0),   w21 = *(const float4*)(v2w + jj0 + 4);
        float4 w30 = *(const float4*)(v3w + jj0),   w31 = *(const float4*)(v3w + jj0 + 4);
#pragma unroll
        for (int i = 0; i < 8; i++) {
            const float* st = stats + (t0 + i) * 8;
            float m = st[0], istd = st[1], mll = st[2], sll = st[3], dmu = st[4];
            float nim = -istd * m;
            float4 r0, r1;
            r0.x = istd * acc[i][0] + nim * ga0.x + mll * w10.x + sll * w20.x + dmu * w30.x + cb0.x;
            r0.y = istd * acc[i][1] + nim * ga0.y + mll * w10.y + sll * w20.y + dmu * w30.y + cb0.y;
            r0.z = istd * acc[i][2] + nim * ga0.z + mll * w10.z + sll * w20.z + dmu * w30.z + cb0.z;
            r0.w = istd * acc[i][3] + nim * ga0.w + mll * w10.w + sll * w20.w + dmu * w30.w + cb0.w;
            r1.x = istd * acc[i][4] + nim * ga1.x + mll * w11.x + sll * w21.x + dmu * w31.x + cb1.x;
            r1.y = istd * acc[i][5] + nim * ga1.y + mll * w11.y + sll * w21.y + dmu * w31.y + cb1.y;
            r1.z = istd * acc[i][6] + nim * ga1.z + mll * w11.z + sll * w21.z + dmu * w31.z + cb1.z;
            r1.w = istd * acc[i][7] + nim * ga1.w + mll * w11.w + sll * w21.w + dmu * w31.w + cb1.w;
            *(float4*)(c1 + (t0 + i) * 128 + jj0) = r0;
            *(float4*)(c1 + (t0 + i) * 128 + jj0 + 4) = r1;
        }
    }
    __syncthreads();
    // Q-side add + silu (ng >= 48)
    if (ng >= 48) {
        int jj0 = j0 - 384;  // in [0,128), step 8
#pragma unroll
        for (int i = 0; i < 8; i++) {
            float* cp = c1 + (t0 + i) * 128 + jj0;
            float4 c0 = *(const float4*)cp;
            float4 cv1 = *(const float4*)(cp + 4);
            c0.x = silu_f(c0.x + acc[i][0]);
            c0.y = silu_f(c0.y + acc[i][1]);
            c0.z = silu_f(c0.z + acc[i][2]);
            c0.w = silu_f(c0.w + acc[i][3]);
            cv1.x = silu_f(cv1.x + acc[i][4]);
            cv1.y = silu_f(cv1.y + acc[i][5]);
            cv1.z = silu_f(cv1.z + acc[i][6]);
            cv1.w = silu_f(cv1.w + acc[i][7]);
            *(float4*)cp = c0;
            *(float4*)(cp + 4) = cv1;
        }
    }
    __syncthreads();

    // --- GEMM1b: base = a1 @ base_w2^T + b2  (32x49, K=256) ---
    for (int o = tid; o < TT * 49; o += 256) {
        int t = o / 49, s = o - t * 49;
        const float* ar = a1 + t * 256;
        const float* wr = bw2 + s * 256;
        float accv = bb2[s];
        for (int k = 0; k < 256; k += 4) {
            float4 av = *(const float4*)(ar + k);
            float4 wv = *(const float4*)(wr + k);
            accv += av.x * wv.x + av.y * wv.y + av.z * wv.z + av.w * wv.w;
        }
        basebuf[o] = accv;
    }
    __syncthreads();

    // --- GEMM2b: c = c1 @ mlp_w2^T + b2  (32x128, K=128) -> cbuf (overlays a1) ---
    float* cbuf = F;  // stride 132
    {
        int j = tid & 127, tg = tid >> 7;
        float accv[16];
#pragma unroll
        for (int tt = 0; tt < 16; tt++) accv[tt] = 0.f;
        const float* wr = mw2 + (size_t)j * 128;
        const float* cr = c1 + tg * 16 * 128;
        for (int k = 0; k < 128; k += 4) {
            float4 wv = *(const float4*)(wr + k);
#pragma unroll
            for (int tt = 0; tt < 16; tt++) {
                float4 cv = *(const float4*)(cr + tt * 128 + k);
                accv[tt] += cv.x * wv.x + cv.y * wv.y + cv.z * wv.z + cv.w * wv.w;
            }
        }
        float b = mb2[j];
        __syncthreads();  // ensure all a1 reads (GEMM1b) done before overlay write
#pragma unroll
        for (int tt = 0; tt < 16; tt++) cbuf[(tg * 16 + tt) * 132 + j] = accv[tt] + b;
    }
    __syncthreads();

    // --- mode logits + softmax(4) -> alpha; write alpha to out ---
    if (tid < 128) {
        int t = tid >> 2, m = tid & 3;
        const float* cr = cbuf + t * 132;
        float e = c4_s[m];
        for (int k = 0; k < 128; k++) e += cr[k] * cheff_s[k * 4 + m];
        float mx = fmaxf(e, __shfl_xor(e, 1));
        mx = fmaxf(mx, __shfl_xor(mx, 2));
        float ev = expf(e - mx);
        float sum = ev + __shfl_xor(ev, 1);
        sum += __shfl_xor(sum, 2);
        float al = ev / sum;
        alpha_s[t * 4 + m] = al;
        out[ALPHA_OFF + (size_t)(tok0 + t) * 4 + m] = al;
    }
    __syncthreads();

    // --- K: masked stage-graph softmax over rows of 7 ---
    if (tid < TT * 7) {
        int t = tid / 7, i = tid - t * 7;
        const float* al = alpha_s + t * 4;
        float sb[7];
#pragma unroll
        for (int s = 0; s < 7; s++)
            sb[s] = al[0] * msw_s[s * 4 + 0] + al[1] * msw_s[s * 4 + 1] +
                    al[2] * msw_s[s * 4 + 2] + al[3] * msw_s[s * 4 + 3];
        const float* br = basebuf + t * 49 + i * 7;
        const int* mrow = sg_s + i * 7;
        float vals[7];
        float mx = -1e30f;
#pragma unroll
        for (int j = 0; j < 7; j++) {
            float vv = br[j] + sb[j];
            vals[j] = mrow[j] ? vv : -1e30f;
            mx = fmaxf(mx, vals[j]);
        }
        float e[7], sum = 0.f;
#pragma unroll
        for (int j = 0; j < 7; j++) {
            e[j] = mrow[j] ? expf(vals[j] - mx) : 0.f;
            sum += e[j];
        }
        float inv = 1.f / sum;
        size_t off = (size_t)(tok0 + t) * 49 + i * 7;
#pragma unroll
        for (int j = 0; j < 7; j++) out[off + j] = e[j] * inv;
    }
}

// ---------------------------------------------------------------------------
extern "C" void kernel_launch(void* const* d_in, const int* in_sizes, int n_in,
                              void* d_out, int out_size, void* d_ws, size_t ws_size,
                              hipStream_t stream) {
    const float* h    = (const float*)d_in[0];
    const float* ex   = (const float*)d_in[1];
    const float* lam  = (const float*)d_in[2];
    const float* mup  = (const float*)d_in[3];
    const float* bw1  = (const float*)d_in[4];
    const float* bb1  = (const float*)d_in[5];
    const float* bw2  = (const float*)d_in[6];
    const float* bb2  = (const float*)d_in[7];
    const float* lng  = (const float*)d_in[8];
    const float* lnb  = (const float*)d_in[9];
    const float* mw1  = (const float*)d_in[10];
    const float* mb1  = (const float*)d_in[11];
    const float* mw2  = (const float*)d_in[12];
    const float* mb2  = (const float*)d_in[13];
    const float* pe   = (const float*)d_in[14];
    const float* chw  = (const float*)d_in[15];
    const float* chb  = (const float*)d_in[16];
    const float* phw  = (const float*)d_in[17];
    const float* phb  = (const float*)d_in[18];
    const float* bil  = (const float*)d_in[19];
    const float* mob  = (const float*)d_in[20];
    const float* msw  = (const float*)d_in[21];
    const int*   sg   = (const int*)d_in[22];
    const int*   pidx = (const int*)d_in[23];
    float* out = (float*)d_out;
    float* ws = (float*)d_ws;

    float* wcat  = ws + WS_WCAT;
    float* gA    = ws + WS_GA;
    float* cbias = ws + WS_CBIAS;
    float* v1    = ws + WS_V1;
    float* v2    = ws + WS_V2;
    float* v3    = ws + WS_V3;
    float* cheff = ws + WS_CHEFF;
    float* c4    = ws + WS_C4;

    hipLaunchKernelGGL(k_prep, dim3(97), dim3(256), 0, stream, bw1, mw1, lng, mb1, lnb, pe,
                       chw, chb, phw, phb, bil, mob, pidx, wcat, gA, cbias, v1, v2, v3,
                       cheff, c4);
    hipLaunchKernelGGL(k_main, dim3(NT / TT), dim3(256), 0, stream, h, ex, lam, mup, bb1, bw2,
                       bb2, mw2, mb2, msw, sg, wcat, gA, cbias, v1, v2, v3, cheff, c4, out);
}

// Round 6
// 507.088 us; speedup vs baseline: 1.5228x; 1.0540x over previous
//
#include <hip/hip_runtime.h>
#include <cstdint>
#include <cstddef>

// ---------------------------------------------------------------------------
// Problem constants
// ---------------------------------------------------------------------------
#define NT      16384      // B*T tokens
#define DIM     768
#define TT      32         // tokens per block
#define KA      64         // A-chunk (k per LDS stage)
#define NCA     (DIM/KA)   // 12 chunks
#define ALPHA_OFF 802816   // NT*49

// ws layout (floats)
#define WS_WCAT   0          // 768*512 = 393216 (+ overrun-read pad into next fields, harmless)
#define WS_GA     393216     // 128
#define WS_CBIAS  393344     // 128
#define WS_V1     393472     // 128
#define WS_V2     393600     // 128
#define WS_V3     393728     // 128
#define WS_CHEFF  393856     // 512 (transposed [k][m])
#define WS_C4     394368     // 4

__device__ __forceinline__ float silu_f(float x) { return x / (1.0f + expf(-x)); }

// ---------------------------------------------------------------------------
// Fused prep kernel, 97 blocks x 256 threads.  (UNCHANGED from round 3)
// Blocks 0..95: 64x64 tile transpose building wcat[k][pos], k<768, PERMUTED
// columns: orig col j (g=j>>3, r=j&7) lives at
//   pos = (r<4) ? g*4+r : 256 + g*4 + (r-4)
// so k_main thread ng's 8 cols {8ng..8ng+7} are two lane-consecutive float4
// slots (4ng and 256+4ng) -> coalesced global stream reads.
// Column sources:
//   j <  256 : base_w1[j][k]
//   j <  384 : mlp_w1[j-256][k] * ln_g[k]     (LN-scale folded in)
//   else     : mlp_w1[j-384][768+k]
// Block 96: small precomputes (gA, cbias, v1..v3, cheff_t, c4).
// ---------------------------------------------------------------------------
__global__ void k_prep(const float* __restrict__ bw1, const float* __restrict__ mw1,
                       const float* __restrict__ g, const float* __restrict__ mb1,
                       const float* __restrict__ lnb, const float* __restrict__ pe,
                       const float* __restrict__ chw, const float* __restrict__ chb,
                       const float* __restrict__ phw, const float* __restrict__ phb,
                       const float* __restrict__ bil, const float* __restrict__ mob,
                       const int* __restrict__ pidxp, float* __restrict__ wcat,
                       float* __restrict__ gA, float* __restrict__ cbias,
                       float* __restrict__ v1, float* __restrict__ v2,
                       float* __restrict__ v3, float* __restrict__ cheff_t,
                       float* __restrict__ c4) {
    __shared__ float tilebuf[64][65];
    __shared__ float u[32];
    int tid = threadIdx.x;

    if (blockIdx.x == 96) {
        int pidx = *pidxp;
        if (tid < 32) u[tid] = pe[pidx * 32 + tid];
        __syncthreads();
        {
            int j = tid >> 1, half = tid & 1;
            const float* row = mw1 + (size_t)j * 1540 + half * 384;
            const float* gp = g + half * 384;
            const float* bp = lnb + half * 384;
            float sg_ = 0.f, sb_ = 0.f;
            for (int k = 0; k < 384; k += 4) {
                float4 rv = *(const float4*)(row + k);
                float4 gv = *(const float4*)(gp + k);
                float4 bv = *(const float4*)(bp + k);
                sg_ += rv.x * gv.x + rv.y * gv.y + rv.z * gv.z + rv.w * gv.w;
                sb_ += rv.x * bv.x + rv.y * bv.y + rv.z * bv.z + rv.w * bv.w;
            }
            sg_ += __shfl_xor(sg_, 1);
            sb_ += __shfl_xor(sb_, 1);
            if (half == 0) {
                const float* rowf = mw1 + (size_t)j * 1540;
                float pf = (float)pidx * (1.0f / 11.0f);
                gA[j] = sg_;
                v1[j] = rowf[1536];
                v2[j] = rowf[1537];
                v3[j] = rowf[1538];
                cbias[j] = sb_ + pf * rowf[1539] + mb1[j];
            }
        }
        for (int idx = tid; idx < 512; idx += 256) {
            int k = idx >> 2, m = idx & 3;
            float s = chw[m * 128 + k];
            for (int kk = 0; kk < 32; kk++) s += u[kk] * bil[(size_t)(m * 32 + kk) * 128 + k];
            cheff_t[k * 4 + m] = s;
        }
        if (tid < 4) {
            float s = chb[tid] + phb[tid] + mob[tid];
            for (int kk = 0; kk < 32; kk++) s += u[kk] * phw[tid * 32 + kk];
            c4[tid] = s;
        }
        return;
    }

    int jt = blockIdx.x & 7, kt = blockIdx.x >> 3;
    int j0 = jt * 64, k0 = kt * 64;

    {   // coalesced read: thread (jl, kc) reads 16 consecutive k of row j0+jl
        int jl = tid >> 2, kc = (tid & 3) * 16;
        int j = j0 + jl;
        const float* src;
        if (j0 < 256)      src = bw1 + (size_t)j * DIM + k0;
        else if (j0 < 384) src = mw1 + (size_t)(j - 256) * 1540 + k0;
        else               src = mw1 + (size_t)(j - 384) * 1540 + 768 + k0;
#pragma unroll
        for (int q = 0; q < 16; q += 4) {
            float4 v = *(const float4*)(src + kc + q);
            tilebuf[jl][kc + q + 0] = v.x;
            tilebuf[jl][kc + q + 1] = v.y;
            tilebuf[jl][kc + q + 2] = v.z;
            tilebuf[jl][kc + q + 3] = v.w;
        }
    }
    __syncthreads();
    {   // permuted write: thread (kl, jc) handles orig cols j0+jc .. j0+jc+15
        int kl = tid >> 2, jc = (tid & 3) * 16;
        int k = k0 + kl;
        float scale = (j0 >= 256 && j0 < 384) ? g[k] : 1.0f;
        int g0 = (j0 + jc) >> 3;  // even group index
        float* dstA = wcat + (size_t)k * 512 + g0 * 4;
        float* dstB = dstA + 256;
        float4 A1, A2, B1, B2;
        A1.x = tilebuf[jc + 0][kl] * scale;  A1.y = tilebuf[jc + 1][kl] * scale;
        A1.z = tilebuf[jc + 2][kl] * scale;  A1.w = tilebuf[jc + 3][kl] * scale;
        B1.x = tilebuf[jc + 4][kl] * scale;  B1.y = tilebuf[jc + 5][kl] * scale;
        B1.z = tilebuf[jc + 6][kl] * scale;  B1.w = tilebuf[jc + 7][kl] * scale;
        A2.x = tilebuf[jc + 8][kl] * scale;  A2.y = tilebuf[jc + 9][kl] * scale;
        A2.z = tilebuf[jc + 10][kl] * scale; A2.w = tilebuf[jc + 11][kl] * scale;
        B2.x = tilebuf[jc + 12][kl] * scale; B2.y = tilebuf[jc + 13][kl] * scale;
        B2.z = tilebuf[jc + 14][kl] * scale; B2.w = tilebuf[jc + 15][kl] * scale;
        *(float4*)(dstA) = A1;
        *(float4*)(dstA + 4) = A2;
        *(float4*)(dstB) = B1;
        *(float4*)(dstB + 4) = B2;
    }
}

// ---------------------------------------------------------------------------
// A-staging helpers. Chunk = 64 k x 64 rows (32 h-tokens | 32 ex-tokens) in
// [k][t'] layout with swizzle t' = (t + 4*(k>>2)) & 63:
//   - staging ds_write_b32: bank = t' % 32 spreads across kq -> conflict-free
//   - compute ds_read_b128 at word k*64 + (arow0 + (k&60))&63 : 16B-aligned,
//     2 distinct addrs per wave (broadcast) -> conflict-free
// Staging global reads: 16 lanes read one 256B row segment -> coalesced.
// ---------------------------------------------------------------------------
__device__ __forceinline__ float4 stage_ld(const float* __restrict__ h,
                                           const float* __restrict__ ex,
                                           int tok0, int kb, int s) {
    int t = s >> 4, kq = s & 15;
    const float* src = (t < 32) ? (h + (size_t)(tok0 + t) * DIM)
                                : (ex + (size_t)(tok0 + t - 32) * DIM);
    return *(const float4*)(src + kb + kq * 4);
}
__device__ __forceinline__ void stage_st(float* buf, int s, float4 v) {
    int t = s >> 4, kq = s & 15;
    int tp = (t + 4 * kq) & 63;
    float* d = buf + kq * 256 + tp;   // word (4*kq+e)*64 + tp
    d[0] = v.x; d[64] = v.y; d[128] = v.z; d[192] = v.w;
}

// ---------------------------------------------------------------------------
// Main fused kernel. 512 blocks x 256 threads, 32 tokens per block.
// W is streamed DIRECTLY from global (wcat is L2/L3-resident; per k-step the
// wave reads two lane-consecutive 1KB segments) with depth-1 prefetch; only
// A is LDS-staged (double-buffered 64-k chunks -> 12 barriers total).
// Thread (ng=tid&63, mg=tid>>6) owns tokens t0..t0+7 and orig cols 8ng..8ng+7
// (permuted wcat slots 4ng, 256+4ng).
// Shared layout (floats), F[14848] = 59.4 KB:
//   [0,8192)      : union { abuf[2][4096] | a1[32][256] | cbuf[32][132] }
//   [8192,12288)  : c1[32][128]
//   [12288,13856) : basebuf[32][49]
//   [13856,14112) : stats[32][8]
//   [14112,14624) : cheff_s[512]
//   [14624,14752) : alpha_s[32][4]
//   [14752,14756) : c4_s
//   [14756,14784) : msw_s[28]
//   [14784,14833) : sg_s[49] (ints)
// ---------------------------------------------------------------------------
__launch_bounds__(256, 2)
__global__ void k_main(const float* __restrict__ h, const float* __restrict__ ex,
                       const float* __restrict__ lam, const float* __restrict__ mup,
                       const float* __restrict__ bb1, const float* __restrict__ bw2,
                       const float* __restrict__ bb2, const float* __restrict__ mw2,
                       const float* __restrict__ mb2, const float* __restrict__ msw,
                       const int* __restrict__ sg, const float* __restrict__ wcat,
                       const float* __restrict__ gA, const float* __restrict__ cbias,
                       const float* __restrict__ v1w, const float* __restrict__ v2w,
                       const float* __restrict__ v3w, const float* __restrict__ cheff_t,
                       const float* __restrict__ c4, float* __restrict__ out) {
    __shared__ float F[14848];
    float* c1      = F + 8192;
    float* basebuf = F + 12288;
    float* stats   = F + 13856;
    float* cheff_s = F + 14112;
    float* alpha_s = F + 14624;
    float* c4_s    = F + 14752;
    float* msw_s   = F + 14756;
    int*   sg_s    = (int*)(F + 14784);

    const int tid = threadIdx.x;
    const int bid = blockIdx.x;
    const int tok0 = bid * TT;

    // --- small constant preloads ---
    if (tid < 49) sg_s[tid] = sg[tid];
    if (tid >= 64 && tid < 92) msw_s[tid - 64] = msw[tid - 64];
    if (tid >= 96 && tid < 100) c4_s[tid - 96] = c4[tid - 96];
    for (int i = tid; i < 512; i += 256) cheff_s[i] = cheff_t[i];

    // --- issue chunk-0 A staging loads early (latency hidden under stats) ---
    float4 s0 = stage_ld(h, ex, tok0, 0, tid);
    float4 s1 = stage_ld(h, ex, tok0, 0, tid + 256);
    float4 s2 = stage_ld(h, ex, tok0, 0, tid + 512);
    float4 s3 = stage_ld(h, ex, tok0, 0, tid + 768);

    // --- stats pass: 8 threads per token ---
    {
        int t = tid >> 3, r = tid & 7;
        const float* hp = h + (size_t)(tok0 + t) * DIM;
        const float* lp = lam + (size_t)(tok0 + t) * DIM;
        const float* mp = mup + (size_t)(tok0 + t) * DIM;
        float sh = 0.f, sh2 = 0.f, sll = 0.f, sll2 = 0.f, sd = 0.f;
        for (int i = 0; i < 24; i++) {
            int k0 = i * 32 + r * 4;
            float4 hv = *(const float4*)(hp + k0);
            float4 lv = *(const float4*)(lp + k0);
            float4 mv = *(const float4*)(mp + k0);
#pragma unroll
            for (int e = 0; e < 4; e++) {
                float hx = (&hv.x)[e];
                float lx = fmaxf((&lv.x)[e], 1e-6f);
                float mx = (&mv.x)[e];
                sh += hx; sh2 += hx * hx;
                float ll = logf(lx);
                sll += ll; sll2 += ll * ll;
                float dd = hx - mx; sd += dd * dd;
            }
        }
#pragma unroll
        for (int off = 1; off < 8; off <<= 1) {
            sh += __shfl_xor(sh, off);  sh2 += __shfl_xor(sh2, off);
            sll += __shfl_xor(sll, off); sll2 += __shfl_xor(sll2, off);
            sd += __shfl_xor(sd, off);
        }
        if (r == 0) {
            float m = sh * (1.f / 768.f);
            float var = sh2 * (1.f / 768.f) - m * m;
            float istd = rsqrtf(var + 1e-5f);
            float mll = sll * (1.f / 768.f);
            float vll = (sll2 - 768.f * mll * mll) * (1.f / 767.f);
            float sstd = fmaxf(sqrtf(fmaxf(vll, 0.f)), 1e-6f);
            float dmu = sqrtf(sd * (1.f / 768.f) + 1e-8f);
            float* st = stats + t * 8;
            st[0] = m; st[1] = istd; st[2] = mll; st[3] = sstd; st[4] = dmu;
        }
    }

    // --- write chunk-0 A into buffer 0 ---
    stage_st(F, tid, s0);
    stage_st(F, tid + 256, s1);
    stage_st(F, tid + 512, s2);
    stage_st(F, tid + 768, s3);
    __syncthreads();

    // --- main GEMM: [32 tok] x [512 outs], K=768 ---
    const int ng = tid & 63, mg = tid >> 6;
    const int j0 = ng * 8, t0 = mg * 8;
    const int arow0 = t0 + ((ng < 48) ? 0 : 32);  // h rows [0,32), ex rows [32,64)

    float acc[8][8] = {};

    int cur = 0;
    for (int c = 0; c < NCA; c++) {
        const int kb = c * KA;
        const bool more = (c + 1 < NCA);
        const float* ab = F + cur * 4096;
        float* nb = F + (cur ^ 1) * 4096;
        const float* wb0 = wcat + (size_t)kb * 512 + ng * 4;

        if (more) {  // first half of next chunk's A
            s0 = stage_ld(h, ex, tok0, kb + KA, tid);
            s1 = stage_ld(h, ex, tok0, kb + KA, tid + 256);
        }

        float4 wl = *(const float4*)(wb0);
        float4 wh = *(const float4*)(wb0 + 256);

#pragma unroll 4
        for (int kk = 0; kk < KA; kk++) {
            // depth-1 W prefetch (final iter reads row kb+64 <= 768: in-ws, unused)
            const float* wn = wb0 + (size_t)(kk + 1) * 512;
            float4 wln = *(const float4*)(wn);
            float4 whn = *(const float4*)(wn + 256);
            const float* ar = ab + kk * 64;
            int tp = (arow0 + (kk & 60)) & 63;
            float4 a0  = *(const float4*)(ar + tp);
            float4 a1v = *(const float4*)(ar + ((tp + 4) & 63));
            float av[8] = {a0.x, a0.y, a0.z, a0.w, a1v.x, a1v.y, a1v.z, a1v.w};
            float wv[8] = {wl.x, wl.y, wl.z, wl.w, wh.x, wh.y, wh.z, wh.w};
#pragma unroll
            for (int i = 0; i < 8; i++)
#pragma unroll
                for (int j = 0; j < 8; j++)
                    acc[i][j] = fmaf(av[i], wv[j], acc[i][j]);
            wl = wln; wh = whn;
            if (kk == 31 && more) {  // midpoint: flush half, load second half
                stage_st(nb, tid, s0);
                stage_st(nb, tid + 256, s1);
                s0 = stage_ld(h, ex, tok0, kb + KA, tid + 512);
                s1 = stage_ld(h, ex, tok0, kb + KA, tid + 768);
            }
        }
        if (more) {
            stage_st(nb, tid + 512, s0);
            stage_st(nb, tid + 768, s1);
        }
        __syncthreads();
        cur ^= 1;
    }

    // --- epilogue part 1: a1 = silu(acc+b1) [ng<32]; c1 P-side [ng in 32..47] ---
    float* a1 = F;  // staging region dead
    if (ng < 32) {
        float4 ba = *(const float4*)(bb1 + j0);
        float4 bb = *(const float4*)(bb1 + j0 + 4);
#pragma unroll
        for (int i = 0; i < 8; i++) {
            float4 v0, v1;
            v0.x = silu_f(acc[i][0] + ba.x);
            v0.y = silu_f(acc[i][1] + ba.y);
            v0.z = silu_f(acc[i][2] + ba.z);
            v0.w = silu_f(acc[i][3] + ba.w);
            v1.x = silu_f(acc[i][4] + bb.x);
            v1.y = silu_f(acc[i][5] + bb.y);
            v1.z = silu_f(acc[i][6] + bb.z);
            v1.w = silu_f(acc[i][7] + bb.w);
            *(float4*)(a1 + (t0 + i) * 256 + j0) = v0;
            *(float4*)(a1 + (t0 + i) * 256 + j0 + 4) = v1;
        }
    } else if (ng < 48) {
        int jj0 = j0 - 256;  // in [0,128), step 8
        float4 ga0 = *(const float4*)(gA + jj0),    ga1 = *(const float4*)(gA + jj0 + 4);
        float4 cb0 = *(const float4*)(cbias + jj0), cb1 = *(const float4*)(cbias + jj0 + 4);
        float4 w10 = *(const float4*)(v1w + jj0),   w11 = *(const float4*)(v1w + jj0 + 4);
        float4 w20 = *(const float4*)(v2w + jj0),   w21 = *(const float4*)(v2w + jj0 + 4);
        float4 w30 = *(const float4*)(v3w + jj0),   w31 = *(const float4*)(v3w + jj0 + 4);
#pragma unroll
        for (int i = 0; i < 8; i++) {
            const float* st = stats + (t0 + i) * 8;
            float m = st[0], istd = st[1], mll = st[2], sll = st[3], dmu = st[4];
            float nim = -istd * m;
            float4 r0, r1;
            r0.x = istd * acc[i][0] + nim * ga0.x + mll * w10.x + sll * w20.x + dmu * w30.x + cb0.x;
            r0.y = istd * acc[i][1] + nim * ga0.y + mll * w10.y + sll * w20.y + dmu * w30.y + cb0.y;
            r0.z = istd * acc[i][2] + nim * ga0.z + mll * w10.z + sll * w20.z + dmu * w30.z + cb0.z;
            r0.w = istd * acc[i][3] + nim * ga0.w + mll * w10.w + sll * w20.w + dmu * w30.w + cb0.w;
            r1.x = istd * acc[i][4] + nim * ga1.x + mll * w11.x + sll * w21.x + dmu * w31.x + cb1.x;
            r1.y = istd * acc[i][5] + nim * ga1.y + mll * w11.y + sll * w21.y + dmu * w31.y + cb1.y;
            r1.z = istd * acc[i][6] + nim * ga1.z + mll * w11.z + sll * w21.z + dmu * w31.z + cb1.z;
            r1.w = istd * acc[i][7] + nim * ga1.w + mll * w11.w + sll * w21.w + dmu * w31.w + cb1.w;
            *(float4*)(c1 + (t0 + i) * 128 + jj0) = r0;
            *(float4*)(c1 + (t0 + i) * 128 + jj0 + 4) = r1;
        }
    }
    __syncthreads();
    // Q-side add + silu (ng >= 48)
    if (ng >= 48) {
        int jj0 = j0 - 384;  // in [0,128), step 8
#pragma unroll
        for (int i = 0; i < 8; i++) {
            float* cp = c1 + (t0 + i) * 128 + jj0;
            float4 c0 = *(const float4*)cp;
            float4 cv1 = *(const float4*)(cp + 4);
            c0.x = silu_f(c0.x + acc[i][0]);
            c0.y = silu_f(c0.y + acc[i][1]);
            c0.z = silu_f(c0.z + acc[i][2]);
            c0.w = silu_f(c0.w + acc[i][3]);
            cv1.x = silu_f(cv1.x + acc[i][4]);
            cv1.y = silu_f(cv1.y + acc[i][5]);
            cv1.z = silu_f(cv1.z + acc[i][6]);
            cv1.w = silu_f(cv1.w + acc[i][7]);
            *(float4*)cp = c0;
            *(float4*)(cp + 4) = cv1;
        }
    }
    __syncthreads();

    // --- GEMM1b: base = a1 @ base_w2^T + b2  (32x49, K=256) ---
    for (int o = tid; o < TT * 49; o += 256) {
        int t = o / 49, s = o - t * 49;
        const float* ar = a1 + t * 256;
        const float* wr = bw2 + s * 256;
        float accv = bb2[s];
        for (int k = 0; k < 256; k += 4) {
            float4 av = *(const float4*)(ar + k);
            float4 wv = *(const float4*)(wr + k);
            accv += av.x * wv.x + av.y * wv.y + av.z * wv.z + av.w * wv.w;
        }
        basebuf[o] = accv;
    }
    __syncthreads();

    // --- GEMM2b: c = c1 @ mlp_w2^T + b2  (32x128, K=128) -> cbuf (overlays a1) ---
    float* cbuf = F;  // stride 132
    {
        int j = tid & 127, tg = tid >> 7;
        float accv[16];
#pragma unroll
        for (int tt = 0; tt < 16; tt++) accv[tt] = 0.f;
        const float* wr = mw2 + (size_t)j * 128;
        const float* cr = c1 + tg * 16 * 128;
        for (int k = 0; k < 128; k += 4) {
            float4 wv = *(const float4*)(wr + k);
#pragma unroll
            for (int tt = 0; tt < 16; tt++) {
                float4 cv = *(const float4*)(cr + tt * 128 + k);
                accv[tt] += cv.x * wv.x + cv.y * wv.y + cv.z * wv.z + cv.w * wv.w;
            }
        }
        float b = mb2[j];
        __syncthreads();  // ensure all a1 reads (GEMM1b) done before overlay write
#pragma unroll
        for (int tt = 0; tt < 16; tt++) cbuf[(tg * 16 + tt) * 132 + j] = accv[tt] + b;
    }
    __syncthreads();

    // --- mode logits + softmax(4) -> alpha; write alpha to out ---
    if (tid < 128) {
        int t = tid >> 2, m = tid & 3;
        const float* cr = cbuf + t * 132;
        float e = c4_s[m];
        for (int k = 0; k < 128; k++) e += cr[k] * cheff_s[k * 4 + m];
        float mx = fmaxf(e, __shfl_xor(e, 1));
        mx = fmaxf(mx, __shfl_xor(mx, 2));
        float ev = expf(e - mx);
        float sum = ev + __shfl_xor(ev, 1);
        sum += __shfl_xor(sum, 2);
        float al = ev / sum;
        alpha_s[t * 4 + m] = al;
        out[ALPHA_OFF + (size_t)(tok0 + t) * 4 + m] = al;
    }
    __syncthreads();

    // --- K: masked stage-graph softmax over rows of 7 ---
    if (tid < TT * 7) {
        int t = tid / 7, i = tid - t * 7;
        const float* al = alpha_s + t * 4;
        float sb[7];
#pragma unroll
        for (int s = 0; s < 7; s++)
            sb[s] = al[0] * msw_s[s * 4 + 0] + al[1] * msw_s[s * 4 + 1] +
                    al[2] * msw_s[s * 4 + 2] + al[3] * msw_s[s * 4 + 3];
        const float* br = basebuf + t * 49 + i * 7;
        const int* mrow = sg_s + i * 7;
        float vals[7];
        float mx = -1e30f;
#pragma unroll
        for (int j = 0; j < 7; j++) {
            float vv = br[j] + sb[j];
            vals[j] = mrow[j] ? vv : -1e30f;
            mx = fmaxf(mx, vals[j]);
        }
        float e[7], sum = 0.f;
#pragma unroll
        for (int j = 0; j < 7; j++) {
            e[j] = mrow[j] ? expf(vals[j] - mx) : 0.f;
            sum += e[j];
        }
        float inv = 1.f / sum;
        size_t off = (size_t)(tok0 + t) * 49 + i * 7;
#pragma unroll
        for (int j = 0; j < 7; j++) out[off + j] = e[j] * inv;
    }
}

// ---------------------------------------------------------------------------
extern "C" void kernel_launch(void* const* d_in, const int* in_sizes, int n_in,
                              void* d_out, int out_size, void* d_ws, size_t ws_size,
                              hipStream_t stream) {
    const float* h    = (const float*)d_in[0];
    const float* ex   = (const float*)d_in[1];
    const float* lam  = (const float*)d_in[2];
    const float* mup  = (const float*)d_in[3];
    const float* bw1  = (const float*)d_in[4];
    const float* bb1  = (const float*)d_in[5];
    const float* bw2  = (const float*)d_in[6];
    const float* bb2  = (const float*)d_in[7];
    const float* lng  = (const float*)d_in[8];
    const float* lnb  = (const float*)d_in[9];
    const float* mw1  = (const float*)d_in[10];
    const float* mb1  = (const float*)d_in[11];
    const float* mw2  = (const float*)d_in[12];
    const float* mb2  = (const float*)d_in[13];
    const float* pe   = (const float*)d_in[14];
    const float* chw  = (const float*)d_in[15];
    const float* chb  = (const float*)d_in[16];
    const float* phw  = (const float*)d_in[17];
    const float* phb  = (const float*)d_in[18];
    const float* bil  = (const float*)d_in[19];
    const float* mob  = (const float*)d_in[20];
    const float* msw  = (const float*)d_in[21];
    const int*   sg   = (const int*)d_in[22];
    const int*   pidx = (const int*)d_in[23];
    float* out = (float*)d_out;
    float* ws = (float*)d_ws;

    float* wcat  = ws + WS_WCAT;
    float* gA    = ws + WS_GA;
    float* cbias = ws + WS_CBIAS;
    float* v1    = ws + WS_V1;
    float* v2    = ws + WS_V2;
    float* v3    = ws + WS_V3;
    float* cheff = ws + WS_CHEFF;
    float* c4    = ws + WS_C4;

    hipLaunchKernelGGL(k_prep, dim3(97), dim3(256), 0, stream, bw1, mw1, lng, mb1, lnb, pe,
                       chw, chb, phw, phb, bil, mob, pidx, wcat, gA, cbias, v1, v2, v3,
                       cheff, c4);
    hipLaunchKernelGGL(k_main, dim3(NT / TT), dim3(256), 0, stream, h, ex, lam, mup, bb1, bw2,
                       bb2, mw2, mb2, msw, sg, wcat, gA, cbias, v1, v2, v3, cheff, c4, out);
}